// Round 1
// baseline (309.578 us; speedup 1.0000x reference)
//
#include <hip/hip_runtime.h>
#include <cstdint>
#include <cstddef>

// Problem constants (DialogueRNNCell: B=4096, T=128, P=2, all feature dims 256)
#define B_N   4096
#define T_N   128
#define P_N   2
#define D     256
#define NG    768                  // 3*D gate width
#define BD    (B_N * D)            // elements per g_hist time slice

// ---------------------------------------------------------------------------
// Fused attention over history: one pass, online softmax. One wave per b.
//   scale[t,b] = dot(g_hist[t,b,:], w);  alpha = softmax_t(scale)
//   c_[b,:]    = sum_t alpha[t,b] * g_hist[t,b,:]
//   alpha_out[b,t] = alpha[t,b]
// ---------------------------------------------------------------------------
__global__ __launch_bounds__(256) void attn_kernel(
    const float* __restrict__ g_hist, const float* __restrict__ attn_w,
    float* __restrict__ c_, float* __restrict__ alpha_out)
{
    const int lane = threadIdx.x & 63;
    const int wid  = threadIdx.x >> 6;
    const int b    = blockIdx.x * 4 + wid;

    const float4 w4 = *reinterpret_cast<const float4*>(attn_w + lane * 4);
    const float* gbase = g_hist + (size_t)b * D + lane * 4;

    float  m = -INFINITY, l = 0.f;
    float4 acc = {0.f, 0.f, 0.f, 0.f};
    float  s0 = 0.f, s1 = 0.f;   // per-lane stash of raw scores (t&63==lane)

    auto step = [&](int t, const float4& g) {
        float dot = g.x * w4.x + g.y * w4.y + g.z * w4.z + g.w * w4.w;
        #pragma unroll
        for (int off = 32; off >= 1; off >>= 1)
            dot += __shfl_xor(dot, off, 64);
        const float mn   = fmaxf(m, dot);
        const float corr = __expf(m - mn);     // t==0: exp(-inf)=0, zeroes stale state
        const float p    = __expf(dot - mn);
        l = l * corr + p;
        acc.x = fmaf(p, g.x, acc.x * corr);
        acc.y = fmaf(p, g.y, acc.y * corr);
        acc.z = fmaf(p, g.z, acc.z * corr);
        acc.w = fmaf(p, g.w, acc.w * corr);
        m = mn;
        if ((t & 63) == lane) { if (t & 64) s1 = dot; else s0 = dot; }
    };

    // unroll-by-2 so both loads issue before the dependent reduce chain
    for (int t = 0; t < T_N; t += 2) {
        const float4 g0 = *reinterpret_cast<const float4*>(gbase + (size_t)t * BD);
        const float4 g1 = *reinterpret_cast<const float4*>(gbase + (size_t)(t + 1) * BD);
        step(t, g0);
        step(t + 1, g1);
    }

    const float rl = 1.f / l;
    float4 cv = {acc.x * rl, acc.y * rl, acc.z * rl, acc.w * rl};
    *reinterpret_cast<float4*>(c_ + (size_t)b * D + lane * 4) = cv;
    alpha_out[(size_t)b * T_N + lane]      = __expf(s0 - m) * rl;
    alpha_out[(size_t)b * T_N + 64 + lane] = __expf(s1 - m) * rl;
}

// ---------------------------------------------------------------------------
// GRU GEMM:  phase z=0: gi = Ai0@Wi0^T (+ Ai1@Wi1^T) + bi   [M x 768]
//            phase z=1: gh = Ah @Wh^T                + bh   [M x 768]
// All A parts are [M x 256] row-major (stride 256). W row stride = ldw.
// f32 VALU, 64x64 tile, 4x4 micro per thread, BK=16 LDS staging.
// ---------------------------------------------------------------------------
#define BM 64
#define BN 64
#define BK 16

__global__ __launch_bounds__(256) void gru_gemm(
    const float* __restrict__ Ai0, const float* __restrict__ Wi0,
    const float* __restrict__ Ai1, const float* __restrict__ Wi1,
    int ldwi, const float* __restrict__ bi,
    const float* __restrict__ Ah,  const float* __restrict__ Wh,
    const float* __restrict__ bh,
    float* __restrict__ gi, float* __restrict__ gh)
{
    const int phase = blockIdx.z;
    const float* pA0  = (phase == 0) ? Ai0 : Ah;
    const float* pA1  = (phase == 0) ? Ai1 : nullptr;
    const float* pW0  = (phase == 0) ? Wi0 : Wh;
    const float* pW1  = (phase == 0) ? Wi1 : nullptr;
    const int    ldw  = (phase == 0) ? ldwi : D;
    const float* bias = (phase == 0) ? bi : bh;
    float*       Cout = (phase == 0) ? gi : gh;

    const int row0 = blockIdx.x * BM;
    const int col0 = blockIdx.y * BN;

    __shared__ float As[BK][BM + 4];
    __shared__ float Bs[BK][BN + 4];

    const int t    = threadIdx.x;
    const int tx   = t & 15;        // micro col group
    const int ty   = t >> 4;        // micro row group
    const int lrow = t >> 2;        // loader: 0..63
    const int lk   = (t & 3) * 4;   // loader: k offset {0,4,8,12}

    float acc[4][4] = {};

    const int nparts = pA1 ? 2 : 1;
    for (int part = 0; part < nparts; ++part) {
        const float* A = part ? pA1 : pA0;
        const float* W = part ? pW1 : pW0;
        for (int kt = 0; kt < D; kt += BK) {
            const float4 av = *reinterpret_cast<const float4*>(
                A + (size_t)(row0 + lrow) * D + kt + lk);
            const float4 wv = *reinterpret_cast<const float4*>(
                W + (size_t)(col0 + lrow) * ldw + kt + lk);
            __syncthreads();
            As[lk + 0][lrow] = av.x; As[lk + 1][lrow] = av.y;
            As[lk + 2][lrow] = av.z; As[lk + 3][lrow] = av.w;
            Bs[lk + 0][lrow] = wv.x; Bs[lk + 1][lrow] = wv.y;
            Bs[lk + 2][lrow] = wv.z; Bs[lk + 3][lrow] = wv.w;
            __syncthreads();
            #pragma unroll
            for (int kk = 0; kk < BK; ++kk) {
                const float4 a4 = *reinterpret_cast<const float4*>(&As[kk][ty * 4]);
                const float4 b4 = *reinterpret_cast<const float4*>(&Bs[kk][tx * 4]);
                const float ar[4] = {a4.x, a4.y, a4.z, a4.w};
                const float br[4] = {b4.x, b4.y, b4.z, b4.w};
                #pragma unroll
                for (int i = 0; i < 4; ++i)
                    #pragma unroll
                    for (int j = 0; j < 4; ++j)
                        acc[i][j] = fmaf(ar[i], br[j], acc[i][j]);
            }
        }
    }

    #pragma unroll
    for (int i = 0; i < 4; ++i) {
        float4 res;
        res.x = acc[i][0] + bias[col0 + tx * 4 + 0];
        res.y = acc[i][1] + bias[col0 + tx * 4 + 1];
        res.z = acc[i][2] + bias[col0 + tx * 4 + 2];
        res.w = acc[i][3] + bias[col0 + tx * 4 + 3];
        *reinterpret_cast<float4*>(
            Cout + (size_t)(row0 + ty * 4 + i) * NG + col0 + tx * 4) = res;
    }
}

// ---------------------------------------------------------------------------
// GRU gate math: out = (1-z)*n + z*h ; optional scatter into q_ speaker slot.
// ---------------------------------------------------------------------------
__global__ __launch_bounds__(256) void gru_gate(
    const float* __restrict__ gi, const float* __restrict__ gh,
    const float* __restrict__ h, float* __restrict__ out,
    float* __restrict__ scatter_base, const int* __restrict__ scatter_idx)
{
    const int i   = blockIdx.x * 256 + threadIdx.x;
    const int row = i >> 8;
    const int j   = i & 255;
    const size_t g0 = (size_t)row * NG + j;

    const float ir = gi[g0], iz = gi[g0 + 256], in_ = gi[g0 + 512];
    const float hr = gh[g0], hz = gh[g0 + 256], hn  = gh[g0 + 512];
    const float hv = h[(size_t)row * D + j];

    const float r = 1.f / (1.f + __expf(-(ir + hr)));
    const float z = 1.f / (1.f + __expf(-(iz + hz)));
    const float n = tanhf(in_ + r * hn);
    const float val = (1.f - z) * n + z * hv;

    out[(size_t)row * D + j] = val;
    if (scatter_idx)
        scatter_base[((size_t)row * P_N + scatter_idx[row]) * D + j] = val;
}

// gather the speaking party's q0 row: q0_sel[b,:] = q0[b, qm[b], :]
__global__ __launch_bounds__(256) void gather_q0(
    const float* __restrict__ q0, const int* __restrict__ qm,
    float* __restrict__ q0_sel)
{
    const int i   = blockIdx.x * 256 + threadIdx.x;   // over B*D/4
    const int row = i >> 6;
    const int j   = (i & 63) * 4;
    const float4 v = *reinterpret_cast<const float4*>(
        q0 + ((size_t)row * P_N + qm[row]) * D + j);
    *reinterpret_cast<float4*>(q0_sel + (size_t)row * D + j) = v;
}

__global__ __launch_bounds__(256) void copy4(
    const float* __restrict__ src, float* __restrict__ dst, int n4)
{
    const int i = blockIdx.x * 256 + threadIdx.x;
    if (i < n4)
        reinterpret_cast<float4*>(dst)[i] =
            reinterpret_cast<const float4*>(src)[i];
}

// ---------------------------------------------------------------------------
extern "C" void kernel_launch(void* const* d_in, const int* in_sizes, int n_in,
                              void* d_out, int out_size, void* d_ws, size_t ws_size,
                              hipStream_t stream)
{
    const float* U      = (const float*)d_in[0];
    const int*   qm     = (const int*)  d_in[1];
    const float* g_hist = (const float*)d_in[2];
    const float* q0     = (const float*)d_in[3];
    const float* e0     = (const float*)d_in[4];
    const float* wg_ih  = (const float*)d_in[5];
    const float* wg_hh  = (const float*)d_in[6];
    const float* bg_ih  = (const float*)d_in[7];
    const float* bg_hh  = (const float*)d_in[8];
    const float* wp_ih  = (const float*)d_in[9];
    const float* wp_hh  = (const float*)d_in[10];
    const float* bp_ih  = (const float*)d_in[11];
    const float* bp_hh  = (const float*)d_in[12];
    const float* we_ih  = (const float*)d_in[13];
    const float* we_hh  = (const float*)d_in[14];
    const float* be_ih  = (const float*)d_in[15];
    const float* be_hh  = (const float*)d_in[16];
    const float* attn_w = (const float*)d_in[17];

    float* out   = (float*)d_out;
    float* g_out = out;                       // [B, 256]
    float* q_out = out + 1048576;             // [B, 2, 256]
    float* e_out = out + 3145728;             // [B, 256]
    float* a_out = out + 4194304;             // [B, 1, 128]

    float* ws    = (float*)d_ws;
    float* c_    = ws;                        // [B,256]
    float* q0sel = ws + 1048576;              // [B,256]
    float* qssel = ws + 2097152;              // [B,256]
    float* gibuf = ws + 3145728;              // [B,768]
    float* ghbuf = ws + 6291456;              // [B,768]

    const float* g_last = g_hist + (size_t)(T_N - 1) * BD;

    const dim3 blk(256);
    const dim3 gridGemm(B_N / BM, NG / BN, 2);

    // independent preludes
    gather_q0<<<B_N * D / 4 / 256, blk, 0, stream>>>(q0, qm, q0sel);
    copy4<<<(B_N * P_N * D / 4 + 255) / 256, blk, 0, stream>>>(q0, q_out, B_N * P_N * D / 4);
    attn_kernel<<<B_N / 4, blk, 0, stream>>>(g_hist, attn_w, c_, a_out);

    // global GRU: x = [U | q0_sel], h = g_hist[-1]
    gru_gemm<<<gridGemm, blk, 0, stream>>>(
        U, wg_ih, q0sel, wg_ih + 256, 512, bg_ih,
        g_last, wg_hh, bg_hh, gibuf, ghbuf);
    gru_gate<<<B_N, blk, 0, stream>>>(gibuf, ghbuf, g_last, g_out, nullptr, nullptr);

    // party GRU (speaker slot only): x = [U | c_], h = q0_sel
    gru_gemm<<<gridGemm, blk, 0, stream>>>(
        U, wp_ih, c_, wp_ih + 256, 512, bp_ih,
        q0sel, wp_hh, bp_hh, gibuf, ghbuf);
    gru_gate<<<B_N, blk, 0, stream>>>(gibuf, ghbuf, q0sel, qssel, q_out, qm);

    // emotion GRU: x = qs_sel, h = e0
    gru_gemm<<<gridGemm, blk, 0, stream>>>(
        qssel, we_ih, nullptr, nullptr, 256, be_ih,
        e0, we_hh, be_hh, gibuf, ghbuf);
    gru_gate<<<B_N, blk, 0, stream>>>(gibuf, ghbuf, e0, e_out, nullptr, nullptr);
}

// Round 2
// 196.501 us; speedup vs baseline: 1.5755x; 1.5755x over previous
//
#include <hip/hip_runtime.h>
#include <hip/hip_bf16.h>
#include <cstdint>
#include <cstddef>

// Problem constants (DialogueRNNCell: B=4096, T=128, P=2, all feature dims 256)
#define B_N   4096
#define T_N   128
#define P_N   2
#define D     256
#define NG    768                  // 3*D gate width
#define BD    (B_N * D)            // elements per g_hist time slice

typedef __attribute__((ext_vector_type(4))) float f32x4;
typedef __attribute__((ext_vector_type(8))) short bf16x8;
typedef __attribute__((ext_vector_type(8))) unsigned short ushort8;

__device__ __forceinline__ unsigned short f2bf(float f) {
    __hip_bfloat16 h = __float2bfloat16(f);
    return *reinterpret_cast<unsigned short*>(&h);
}

// ---------------------------------------------------------------------------
// Batched f32 -> bf16 conversion (weights + U + e0 + g_last), 8 elems/thread
// ---------------------------------------------------------------------------
struct CvtJobs {
    const float*     src[9];
    unsigned short*  dst[9];
    int              n[9];
};

__global__ __launch_bounds__(256) void cvt_batch(CvtJobs jobs)
{
    const int j = blockIdx.y;
    const int i = (blockIdx.x * 256 + threadIdx.x) * 8;
    if (i >= jobs.n[j]) return;
    const float4* s = reinterpret_cast<const float4*>(jobs.src[j] + i);
    const float4 v0 = s[0], v1 = s[1];
    ushort8 o = { f2bf(v0.x), f2bf(v0.y), f2bf(v0.z), f2bf(v0.w),
                  f2bf(v1.x), f2bf(v1.y), f2bf(v1.z), f2bf(v1.w) };
    *reinterpret_cast<ushort8*>(jobs.dst[j] + i) = o;
}

// ---------------------------------------------------------------------------
// Fused attention over history: one pass, online softmax. One wave per b.
// c_ is emitted in bf16 (only consumed as a GEMM operand).
// ---------------------------------------------------------------------------
__global__ __launch_bounds__(256) void attn_kernel(
    const float* __restrict__ g_hist, const float* __restrict__ attn_w,
    unsigned short* __restrict__ c_bf, float* __restrict__ alpha_out)
{
    const int lane = threadIdx.x & 63;
    const int wid  = threadIdx.x >> 6;
    const int b    = blockIdx.x * 4 + wid;

    const float4 w4 = *reinterpret_cast<const float4*>(attn_w + lane * 4);
    const float* gbase = g_hist + (size_t)b * D + lane * 4;

    float  m = -INFINITY, l = 0.f;
    float4 acc = {0.f, 0.f, 0.f, 0.f};
    float  s0 = 0.f, s1 = 0.f;   // per-lane stash of raw scores (t&63==lane)

    auto step = [&](int t, const float4& g) {
        float dot = g.x * w4.x + g.y * w4.y + g.z * w4.z + g.w * w4.w;
        #pragma unroll
        for (int off = 32; off >= 1; off >>= 1)
            dot += __shfl_xor(dot, off, 64);
        const float mn   = fmaxf(m, dot);
        const float corr = __expf(m - mn);     // t==0: exp(-inf)=0, zeroes stale state
        const float p    = __expf(dot - mn);
        l = l * corr + p;
        acc.x = fmaf(p, g.x, acc.x * corr);
        acc.y = fmaf(p, g.y, acc.y * corr);
        acc.z = fmaf(p, g.z, acc.z * corr);
        acc.w = fmaf(p, g.w, acc.w * corr);
        m = mn;
        if ((t & 63) == lane) { if (t & 64) s1 = dot; else s0 = dot; }
    };

    for (int t = 0; t < T_N; t += 2) {
        const float4 g0 = *reinterpret_cast<const float4*>(gbase + (size_t)t * BD);
        const float4 g1 = *reinterpret_cast<const float4*>(gbase + (size_t)(t + 1) * BD);
        step(t, g0);
        step(t + 1, g1);
    }

    const float rl = 1.f / l;
    ushort4 cv = { f2bf(acc.x * rl), f2bf(acc.y * rl),
                   f2bf(acc.z * rl), f2bf(acc.w * rl) };
    *reinterpret_cast<ushort4*>(c_bf + (size_t)b * D + lane * 4) = cv;
    alpha_out[(size_t)b * T_N + lane]      = __expf(s0 - m) * rl;
    alpha_out[(size_t)b * T_N + 64 + lane] = __expf(s1 - m) * rl;
}

// ---------------------------------------------------------------------------
// MFMA GRU GEMM. phase z=0: gi = [A0|A1] @ Wi^T + bi   (K=Ki)
//                phase z=1: gh = Ah @ Wh^T      + bh   (K=256)
// A parts are [M x 256] bf16 row-major. W is [768 x ldw] bf16 row-major.
// 128x128 tile, BK=32, 4 waves (2x2), 16x16x32 MFMA, global_load_lds w=16.
// LDS 16B-slot XOR swizzle: phys_slot = s ^ ((row>>1)&3), applied on the
// global SOURCE (linear LDS dest) and on the ds_read side.
// ---------------------------------------------------------------------------
__global__ __launch_bounds__(256) void gru_gemm_mfma(
    const unsigned short* __restrict__ A0, const unsigned short* __restrict__ A1,
    const unsigned short* __restrict__ Wi, int ldwi, int Ki,
    const float* __restrict__ bi,
    const unsigned short* __restrict__ Ah, const unsigned short* __restrict__ Wh,
    const float* __restrict__ bh,
    float* __restrict__ gi, float* __restrict__ gh)
{
    const int phase = blockIdx.z;
    const unsigned short* W = phase ? Wh : Wi;
    const int ldw  = phase ? D : ldwi;
    const int K    = phase ? D : Ki;
    const float* bias = phase ? bh : bi;
    float* Cout    = phase ? gh : gi;

    const int r0 = blockIdx.x * 128;
    const int n0 = blockIdx.y * 128;

    __shared__ unsigned short As[128 * 32];
    __shared__ unsigned short Bs[128 * 32];

    const int tid  = threadIdx.x;
    const int lane = tid & 63;
    const int wid  = tid >> 6;
    const int wr   = wid >> 1, wc = wid & 1;

    // staging geometry: per wave 2 calls x 1024B; dest row/slot:
    const int st_row_in_call = lane >> 2;       // 0..15
    const int st_p           = lane & 3;        // physical 16B slot in row

    f32x4 acc[4][4] = {};

    for (int kt = 0; kt < K; kt += 32) {
        const unsigned short* Asrc;
        if (phase) {
            Asrc = Ah + (size_t)r0 * D + kt;
        } else {
            const unsigned short* Ap = (kt < D) ? A0 : A1;
            Asrc = Ap + (size_t)r0 * D + (kt & (D - 1));
        }
        const unsigned short* Wsrc = W + (size_t)n0 * ldw + kt;

        #pragma unroll
        for (int c = 0; c < 2; ++c) {
            const int row = wid * 32 + c * 16 + st_row_in_call;   // 0..127
            const int scol = (st_p ^ ((row >> 1) & 3)) * 8;       // source elems
            __builtin_amdgcn_global_load_lds(
                (const __attribute__((address_space(1))) void*)
                    (Asrc + (size_t)row * D + scol),
                (__attribute__((address_space(3))) void*)
                    (As + wid * 1024 + c * 512), 16, 0, 0);
            __builtin_amdgcn_global_load_lds(
                (const __attribute__((address_space(1))) void*)
                    (Wsrc + (size_t)row * ldw + scol),
                (__attribute__((address_space(3))) void*)
                    (Bs + wid * 1024 + c * 512), 16, 0, 0);
        }
        __syncthreads();

        const int s  = lane >> 4;        // logical k-slot 0..3
        const int fr = lane & 15;        // fragment row/col within 16
        bf16x8 a[4], b[4];
        #pragma unroll
        for (int m = 0; m < 4; ++m) {
            const int row = wr * 64 + m * 16 + fr;
            const int ph  = s ^ ((row >> 1) & 3);
            a[m] = *reinterpret_cast<const bf16x8*>(&As[row * 32 + ph * 8]);
        }
        #pragma unroll
        for (int n = 0; n < 4; ++n) {
            const int row = wc * 64 + n * 16 + fr;
            const int ph  = s ^ ((row >> 1) & 3);
            b[n] = *reinterpret_cast<const bf16x8*>(&Bs[row * 32 + ph * 8]);
        }
        #pragma unroll
        for (int m = 0; m < 4; ++m)
            #pragma unroll
            for (int n = 0; n < 4; ++n)
                acc[m][n] = __builtin_amdgcn_mfma_f32_16x16x32_bf16(
                    a[m], b[n], acc[m][n], 0, 0, 0);
        __syncthreads();
    }

    const int cr = (lane >> 4) * 4;
    const int cc = lane & 15;
    #pragma unroll
    for (int m = 0; m < 4; ++m) {
        #pragma unroll
        for (int n = 0; n < 4; ++n) {
            const int col = n0 + wc * 64 + n * 16 + cc;
            const float bv = bias[col];
            #pragma unroll
            for (int q = 0; q < 4; ++q) {
                const int row = r0 + wr * 64 + m * 16 + cr + q;
                Cout[(size_t)row * NG + col] = acc[m][n][q] + bv;
            }
        }
    }
}

// ---------------------------------------------------------------------------
// GRU gate math: val = (1-z)*n + z*h
// optional f32 out, optional bf16 out, optional scatter into q_ speaker slot
// ---------------------------------------------------------------------------
__global__ __launch_bounds__(256) void gru_gate(
    const float* __restrict__ gi, const float* __restrict__ gh,
    const float* __restrict__ h,
    float* __restrict__ out_f32, unsigned short* __restrict__ out_bf,
    float* __restrict__ scatter_base, const int* __restrict__ scatter_idx)
{
    const int i   = blockIdx.x * 256 + threadIdx.x;
    const int row = i >> 8;
    const int j   = i & 255;
    const size_t g0 = (size_t)row * NG + j;

    const float ir = gi[g0], iz = gi[g0 + 256], in_ = gi[g0 + 512];
    const float hr = gh[g0], hz = gh[g0 + 256], hn  = gh[g0 + 512];
    const float hv = h[(size_t)row * D + j];

    const float r = 1.f / (1.f + __expf(-(ir + hr)));
    const float z = 1.f / (1.f + __expf(-(iz + hz)));
    const float n = tanhf(in_ + r * hn);
    const float val = (1.f - z) * n + z * hv;

    if (out_f32) out_f32[(size_t)row * D + j] = val;
    if (out_bf)  out_bf[(size_t)row * D + j]  = f2bf(val);
    if (scatter_idx)
        scatter_base[((size_t)row * P_N + scatter_idx[row]) * D + j] = val;
}

// gather the speaking party's q0 row into f32 and bf16
__global__ __launch_bounds__(256) void gather_q0(
    const float* __restrict__ q0, const int* __restrict__ qm,
    float* __restrict__ q0_sel, unsigned short* __restrict__ q0_sel_bf)
{
    const int i   = blockIdx.x * 256 + threadIdx.x;   // over B*D/4
    const int row = i >> 6;
    const int j   = (i & 63) * 4;
    const float4 v = *reinterpret_cast<const float4*>(
        q0 + ((size_t)row * P_N + qm[row]) * D + j);
    *reinterpret_cast<float4*>(q0_sel + (size_t)row * D + j) = v;
    ushort4 bv = { f2bf(v.x), f2bf(v.y), f2bf(v.z), f2bf(v.w) };
    *reinterpret_cast<ushort4*>(q0_sel_bf + (size_t)row * D + j) = bv;
}

__global__ __launch_bounds__(256) void copy4(
    const float* __restrict__ src, float* __restrict__ dst, int n4)
{
    const int i = blockIdx.x * 256 + threadIdx.x;
    if (i < n4)
        reinterpret_cast<float4*>(dst)[i] =
            reinterpret_cast<const float4*>(src)[i];
}

// ---------------------------------------------------------------------------
extern "C" void kernel_launch(void* const* d_in, const int* in_sizes, int n_in,
                              void* d_out, int out_size, void* d_ws, size_t ws_size,
                              hipStream_t stream)
{
    const float* U      = (const float*)d_in[0];
    const int*   qm     = (const int*)  d_in[1];
    const float* g_hist = (const float*)d_in[2];
    const float* q0     = (const float*)d_in[3];
    const float* e0     = (const float*)d_in[4];
    const float* wg_ih  = (const float*)d_in[5];
    const float* wg_hh  = (const float*)d_in[6];
    const float* bg_ih  = (const float*)d_in[7];
    const float* bg_hh  = (const float*)d_in[8];
    const float* wp_ih  = (const float*)d_in[9];
    const float* wp_hh  = (const float*)d_in[10];
    const float* bp_ih  = (const float*)d_in[11];
    const float* bp_hh  = (const float*)d_in[12];
    const float* we_ih  = (const float*)d_in[13];
    const float* we_hh  = (const float*)d_in[14];
    const float* be_ih  = (const float*)d_in[15];
    const float* be_hh  = (const float*)d_in[16];
    const float* attn_w = (const float*)d_in[17];

    float* out   = (float*)d_out;
    float* g_out = out;                       // [B, 256]
    float* q_out = out + 1048576;             // [B, 2, 256]
    float* e_out = out + 3145728;             // [B, 256]
    float* a_out = out + 4194304;             // [B, 1, 128]

    // workspace layout
    float* ws     = (float*)d_ws;
    float* gibuf  = ws;                       // [B,768]
    float* ghbuf  = ws + 3145728;             // [B,768]
    float* q0self = ws + 6291456;             // [B,256] f32
    unsigned short* bf = (unsigned short*)(ws + 7340032);
    unsigned short* U_bf     = bf;                 // 1048576
    unsigned short* e0_bf    = bf + 1048576;
    unsigned short* glast_bf = bf + 2097152;
    unsigned short* q0sel_bf = bf + 3145728;
    unsigned short* c_bf     = bf + 4194304;
    unsigned short* qssel_bf = bf + 5242880;
    unsigned short* wgih_bf  = bf + 6291456;       // 393216
    unsigned short* wpih_bf  = bf + 6684672;       // 393216
    unsigned short* wghh_bf  = bf + 7077888;       // 196608
    unsigned short* wphh_bf  = bf + 7274496;
    unsigned short* weih_bf  = bf + 7471104;
    unsigned short* wehh_bf  = bf + 7667712;       // end 7864320

    const float* g_last = g_hist + (size_t)(T_N - 1) * BD;

    const dim3 blk(256);
    const dim3 gridGemm(B_N / 128, NG / 128, 2);

    CvtJobs jobs;
    jobs.src[0] = wg_ih;  jobs.dst[0] = wgih_bf;  jobs.n[0] = NG * 512;
    jobs.src[1] = wg_hh;  jobs.dst[1] = wghh_bf;  jobs.n[1] = NG * 256;
    jobs.src[2] = wp_ih;  jobs.dst[2] = wpih_bf;  jobs.n[2] = NG * 512;
    jobs.src[3] = wp_hh;  jobs.dst[3] = wphh_bf;  jobs.n[3] = NG * 256;
    jobs.src[4] = we_ih;  jobs.dst[4] = weih_bf;  jobs.n[4] = NG * 256;
    jobs.src[5] = we_hh;  jobs.dst[5] = wehh_bf;  jobs.n[5] = NG * 256;
    jobs.src[6] = U;      jobs.dst[6] = U_bf;     jobs.n[6] = B_N * D;
    jobs.src[7] = e0;     jobs.dst[7] = e0_bf;    jobs.n[7] = B_N * D;
    jobs.src[8] = g_last; jobs.dst[8] = glast_bf; jobs.n[8] = B_N * D;
    cvt_batch<<<dim3(B_N * D / 8 / 256, 9), blk, 0, stream>>>(jobs);

    gather_q0<<<B_N * D / 4 / 256, blk, 0, stream>>>(q0, qm, q0self, q0sel_bf);
    copy4<<<(B_N * P_N * D / 4 + 255) / 256, blk, 0, stream>>>(
        q0, q_out, B_N * P_N * D / 4);
    attn_kernel<<<B_N / 4, blk, 0, stream>>>(g_hist, attn_w, c_bf, a_out);

    // global GRU: x = [U | q0_sel], h = g_hist[-1]
    gru_gemm_mfma<<<gridGemm, blk, 0, stream>>>(
        U_bf, q0sel_bf, wgih_bf, 512, 512, bg_ih,
        glast_bf, wghh_bf, bg_hh, gibuf, ghbuf);
    gru_gate<<<B_N, blk, 0, stream>>>(
        gibuf, ghbuf, g_last, g_out, nullptr, nullptr, nullptr);

    // party GRU (speaker slot only): x = [U | c_], h = q0_sel
    gru_gemm_mfma<<<gridGemm, blk, 0, stream>>>(
        U_bf, c_bf, wpih_bf, 512, 512, bp_ih,
        q0sel_bf, wphh_bf, bp_hh, gibuf, ghbuf);
    gru_gate<<<B_N, blk, 0, stream>>>(
        gibuf, ghbuf, q0self, nullptr, qssel_bf, q_out, qm);

    // emotion GRU: x = qs_sel, h = e0
    gru_gemm_mfma<<<gridGemm, blk, 0, stream>>>(
        qssel_bf, nullptr, weih_bf, 256, 256, be_ih,
        e0_bf, wehh_bf, be_hh, gibuf, ghbuf);
    gru_gate<<<B_N, blk, 0, stream>>>(
        gibuf, ghbuf, e0, e_out, nullptr, nullptr, nullptr);
}

// Round 4
// 184.525 us; speedup vs baseline: 1.6777x; 1.0649x over previous
//
#include <hip/hip_runtime.h>
#include <hip/hip_bf16.h>
#include <cstdint>
#include <cstddef>

// Problem constants (DialogueRNNCell: B=4096, T=128, P=2, all feature dims 256)
#define B_N   4096
#define T_N   128
#define P_N   2
#define D     256
#define NG    768                  // 3*D gate width
#define BD    (B_N * D)            // elements per g_hist time slice

typedef __attribute__((ext_vector_type(4))) float f32x4;
typedef __attribute__((ext_vector_type(8))) short bf16x8;
typedef __attribute__((ext_vector_type(8))) unsigned short ushort8;

__device__ __forceinline__ unsigned short f2bf(float f) {
    __hip_bfloat16 h = __float2bfloat16(f);
    return *reinterpret_cast<unsigned short*>(&h);
}

// ---------------------------------------------------------------------------
// Batched f32 -> bf16 conversion (weights + U + e0 + g_last), 8 elems/thread
// ---------------------------------------------------------------------------
struct CvtJobs {
    const float*     src[9];
    unsigned short*  dst[9];
    int              n[9];
};

__global__ __launch_bounds__(256) void cvt_batch(CvtJobs jobs)
{
    const int j = blockIdx.y;
    const int i = (blockIdx.x * 256 + threadIdx.x) * 8;
    if (i >= jobs.n[j]) return;
    const float4* s = reinterpret_cast<const float4*>(jobs.src[j] + i);
    const float4 v0 = s[0], v1 = s[1];
    ushort8 o = { f2bf(v0.x), f2bf(v0.y), f2bf(v0.z), f2bf(v0.w),
                  f2bf(v1.x), f2bf(v1.y), f2bf(v1.z), f2bf(v1.w) };
    *reinterpret_cast<ushort8*>(jobs.dst[j] + i) = o;
}

// ---------------------------------------------------------------------------
// Fused attention over history: one pass, online softmax. One wave per b.
// c_ emitted in bf16 (only consumed as a GEMM operand).
// ---------------------------------------------------------------------------
__global__ __launch_bounds__(256) void attn_kernel(
    const float* __restrict__ g_hist, const float* __restrict__ attn_w,
    unsigned short* __restrict__ c_bf, float* __restrict__ alpha_out)
{
    const int lane = threadIdx.x & 63;
    const int wid  = threadIdx.x >> 6;
    const int b    = blockIdx.x * 4 + wid;

    const float4 w4 = *reinterpret_cast<const float4*>(attn_w + lane * 4);
    const float* gbase = g_hist + (size_t)b * D + lane * 4;

    float  m = -INFINITY, l = 0.f;
    float4 acc = {0.f, 0.f, 0.f, 0.f};
    float  s0 = 0.f, s1 = 0.f;   // per-lane stash of raw scores (t&63==lane)

    auto step = [&](int t, const float4& g) {
        float dot = g.x * w4.x + g.y * w4.y + g.z * w4.z + g.w * w4.w;
        #pragma unroll
        for (int off = 32; off >= 1; off >>= 1)
            dot += __shfl_xor(dot, off, 64);
        const float mn   = fmaxf(m, dot);
        const float corr = __expf(m - mn);     // t==0: exp(-inf)=0, zeroes stale state
        const float p    = __expf(dot - mn);
        l = l * corr + p;
        acc.x = fmaf(p, g.x, acc.x * corr);
        acc.y = fmaf(p, g.y, acc.y * corr);
        acc.z = fmaf(p, g.z, acc.z * corr);
        acc.w = fmaf(p, g.w, acc.w * corr);
        m = mn;
        if ((t & 63) == lane) { if (t & 64) s1 = dot; else s0 = dot; }
    };

    for (int t = 0; t < T_N; t += 2) {
        const float4 g0 = *reinterpret_cast<const float4*>(gbase + (size_t)t * BD);
        const float4 g1 = *reinterpret_cast<const float4*>(gbase + (size_t)(t + 1) * BD);
        step(t, g0);
        step(t + 1, g1);
    }

    const float rl = 1.f / l;
    ushort4 cv = { f2bf(acc.x * rl), f2bf(acc.y * rl),
                   f2bf(acc.z * rl), f2bf(acc.w * rl) };
    *reinterpret_cast<ushort4*>(c_bf + (size_t)b * D + lane * 4) = cv;
    alpha_out[(size_t)b * T_N + lane]      = __expf(s0 - m) * rl;
    alpha_out[(size_t)b * T_N + 64 + lane] = __expf(s1 - m) * rl;
}

// ---------------------------------------------------------------------------
// Fully fused GRU: GEMM (gi = [A0|A1]@Wi^T, gh = Ah@Wh^T) + gate epilogue.
// Block = 128 rows x 32 gate-cols; computes W rows {c0,c0+256,c0+512}+32
// for BOTH gi and gh, then applies the gate math in-register.
//   MODE 0: out_f32[row*256+col] = val        (h = hsrc[row*256+col])
//   MODE 1: party — h = q0[row,qm,col]; writes q_out both slots + qs bf16
// 16x16x32 MFMA, BK=32, 4 waves (each owns 32 rows x 96 cols),
// global_load_lds w=16 with 16B-slot XOR swizzle (phys = s ^ ((row>>1)&3)),
// swizzle applied on the global SOURCE (linear LDS dest) and on ds_read.
// NOTE: kcolA (wraps per A-part) and kcolW (monotone in kt) are SEPARATE —
// collapsing them was round-3's correctness bug.
// ---------------------------------------------------------------------------
template<int MODE>
__global__ __launch_bounds__(256) void fused_gru(
    const unsigned short* __restrict__ A0,
    const unsigned short* __restrict__ A1,   // second K half (Ki==512) or unused
    const unsigned short* __restrict__ Wi, int ldwi, int Ki,
    const float* __restrict__ bi,
    const unsigned short* __restrict__ Ah,
    const unsigned short* __restrict__ Wh,
    const float* __restrict__ bh,
    const float* __restrict__ hsrc,          // MODE0: [M,256]; MODE1: q0 [M,2,256]
    const int*  __restrict__ qm,             // MODE1 only
    float* __restrict__ out_f32,             // MODE0: [M,256]; MODE1: q_out [M,2,256]
    unsigned short* __restrict__ out_bf)     // MODE1: qs_sel bf16
{
    const int r0 = blockIdx.x * 128;
    const int c0 = blockIdx.y * 32;

    __shared__ unsigned short As[128 * 32];
    __shared__ unsigned short Ws[128 * 32];

    const int tid  = threadIdx.x;
    const int lane = tid & 63;
    const int wid  = tid >> 6;

    const int st_row = lane >> 2;       // 0..15 (row within 16-row call)
    const int st_p   = lane & 3;        // physical 16B slot in row

    f32x4 accI[2][6] = {};
    f32x4 accH[2][6] = {};

    // one BK=32 step: stage A rows (col kcolA) and W gate-rows (col kcolW)
    auto kstep = [&](const unsigned short* Apart, int kcolA, int kcolW,
                     const unsigned short* W, int ldw, f32x4 (&acc)[2][6]) {
        #pragma unroll
        for (int c = 0; c < 2; ++c) {
            const int row  = wid * 32 + c * 16 + st_row;          // 0..127
            const int scol = (st_p ^ ((row >> 1) & 3)) * 8;       // swizzled src
            __builtin_amdgcn_global_load_lds(
                (const __attribute__((address_space(1))) void*)
                    (Apart + (size_t)(r0 + row) * D + kcolA + scol),
                (__attribute__((address_space(3))) void*)
                    (As + wid * 1024 + c * 512), 16, 0, 0);
            int grp = row >> 5; if (grp == 3) grp = 2;            // pad rows dup
            const int wrow = grp * 256 + c0 + (row & 31);
            __builtin_amdgcn_global_load_lds(
                (const __attribute__((address_space(1))) void*)
                    (W + (size_t)wrow * ldw + kcolW + scol),
                (__attribute__((address_space(3))) void*)
                    (Ws + wid * 1024 + c * 512), 16, 0, 0);
        }
        __syncthreads();

        const int s  = lane >> 4;        // logical k-slot 0..3
        const int fr = lane & 15;
        bf16x8 a[2], b[6];
        #pragma unroll
        for (int m = 0; m < 2; ++m) {
            const int row = wid * 32 + m * 16 + fr;
            const int ph  = s ^ ((row >> 1) & 3);
            a[m] = *reinterpret_cast<const bf16x8*>(&As[row * 32 + ph * 8]);
        }
        #pragma unroll
        for (int j = 0; j < 6; ++j) {
            const int row = j * 16 + fr;
            const int ph  = s ^ ((row >> 1) & 3);
            b[j] = *reinterpret_cast<const bf16x8*>(&Ws[row * 32 + ph * 8]);
        }
        #pragma unroll
        for (int m = 0; m < 2; ++m)
            #pragma unroll
            for (int j = 0; j < 6; ++j)
                acc[m][j] = __builtin_amdgcn_mfma_f32_16x16x32_bf16(
                    a[m], b[j], acc[m][j], 0, 0, 0);
        __syncthreads();
    };

    for (int kt = 0; kt < Ki; kt += 32) {
        const unsigned short* Ap = (kt < D) ? A0 : A1;
        kstep(Ap, kt & (D - 1), kt, Wi, ldwi, accI);
    }
    for (int kt = 0; kt < D; kt += 32)
        kstep(Ah, kt, kt, Wh, D, accH);

    // ---- gate epilogue (thread-local: r/z/n fragments share (row,col)) ----
    const int cr = (lane >> 4) * 4;
    const int cc = lane & 15;
    #pragma unroll
    for (int m = 0; m < 2; ++m) {
        #pragma unroll
        for (int jj = 0; jj < 2; ++jj) {
            const int col = c0 + jj * 16 + cc;
            const float bir = bi[col],       bhr = bh[col];
            const float biz = bi[col + 256], bhz = bh[col + 256];
            const float bin = bi[col + 512], bhn = bh[col + 512];
            #pragma unroll
            for (int q = 0; q < 4; ++q) {
                const int row = r0 + wid * 32 + m * 16 + cr + q;
                const float ir  = accI[m][jj][q]     + bir;
                const float hr  = accH[m][jj][q]     + bhr;
                const float iz  = accI[m][jj + 2][q] + biz;
                const float hz  = accH[m][jj + 2][q] + bhz;
                const float in_ = accI[m][jj + 4][q] + bin;
                const float hn  = accH[m][jj + 4][q] + bhn;
                const float rg = 1.f / (1.f + __expf(-(ir + hr)));
                const float zg = 1.f / (1.f + __expf(-(iz + hz)));
                const float ng = tanhf(in_ + rg * hn);
                if (MODE == 1) {
                    const int p = qm[row];
                    const float hv  = hsrc[(size_t)row * 512 + (size_t)p * 256 + col];
                    const float ov  = hsrc[(size_t)row * 512 + (size_t)(1 - p) * 256 + col];
                    const float val = (1.f - zg) * ng + zg * hv;
                    out_f32[(size_t)row * 512 + (size_t)p * 256 + col]       = val;
                    out_f32[(size_t)row * 512 + (size_t)(1 - p) * 256 + col] = ov;
                    out_bf[(size_t)row * 256 + col] = f2bf(val);
                } else {
                    const float hv  = hsrc[(size_t)row * 256 + col];
                    const float val = (1.f - zg) * ng + zg * hv;
                    out_f32[(size_t)row * 256 + col] = val;
                }
            }
        }
    }
}

// gather the speaking party's q0 row -> bf16 (GEMM operand only)
__global__ __launch_bounds__(256) void gather_q0(
    const float* __restrict__ q0, const int* __restrict__ qm,
    unsigned short* __restrict__ q0_sel_bf)
{
    const int i   = blockIdx.x * 256 + threadIdx.x;   // over B*D/4
    const int row = i >> 6;
    const int j   = (i & 63) * 4;
    const float4 v = *reinterpret_cast<const float4*>(
        q0 + ((size_t)row * P_N + qm[row]) * D + j);
    ushort4 bv = { f2bf(v.x), f2bf(v.y), f2bf(v.z), f2bf(v.w) };
    *reinterpret_cast<ushort4*>(q0_sel_bf + (size_t)row * D + j) = bv;
}

// ---------------------------------------------------------------------------
extern "C" void kernel_launch(void* const* d_in, const int* in_sizes, int n_in,
                              void* d_out, int out_size, void* d_ws, size_t ws_size,
                              hipStream_t stream)
{
    const float* U      = (const float*)d_in[0];
    const int*   qm     = (const int*)  d_in[1];
    const float* g_hist = (const float*)d_in[2];
    const float* q0     = (const float*)d_in[3];
    const float* e0     = (const float*)d_in[4];
    const float* wg_ih  = (const float*)d_in[5];
    const float* wg_hh  = (const float*)d_in[6];
    const float* bg_ih  = (const float*)d_in[7];
    const float* bg_hh  = (const float*)d_in[8];
    const float* wp_ih  = (const float*)d_in[9];
    const float* wp_hh  = (const float*)d_in[10];
    const float* bp_ih  = (const float*)d_in[11];
    const float* bp_hh  = (const float*)d_in[12];
    const float* we_ih  = (const float*)d_in[13];
    const float* we_hh  = (const float*)d_in[14];
    const float* be_ih  = (const float*)d_in[15];
    const float* be_hh  = (const float*)d_in[16];
    const float* attn_w = (const float*)d_in[17];

    float* out   = (float*)d_out;
    float* g_out = out;                       // [B, 256]
    float* q_out = out + 1048576;             // [B, 2, 256]
    float* e_out = out + 3145728;             // [B, 256]
    float* a_out = out + 4194304;             // [B, 1, 128]

    // workspace: all bf16 staging buffers
    unsigned short* bf = (unsigned short*)d_ws;
    unsigned short* U_bf     = bf;                 // 1048576
    unsigned short* e0_bf    = bf + 1048576;
    unsigned short* glast_bf = bf + 2097152;
    unsigned short* q0sel_bf = bf + 3145728;
    unsigned short* c_bf     = bf + 4194304;
    unsigned short* qssel_bf = bf + 5242880;
    unsigned short* wgih_bf  = bf + 6291456;       // 393216
    unsigned short* wpih_bf  = bf + 6684672;       // 393216
    unsigned short* wghh_bf  = bf + 7077888;       // 196608
    unsigned short* wphh_bf  = bf + 7274496;
    unsigned short* weih_bf  = bf + 7471104;
    unsigned short* wehh_bf  = bf + 7667712;       // end 7864320 elems (15.7 MB)

    const float* g_last = g_hist + (size_t)(T_N - 1) * BD;

    const dim3 blk(256);
    const dim3 gridGru(B_N / 128, D / 32);

    CvtJobs jobs;
    jobs.src[0] = wg_ih;  jobs.dst[0] = wgih_bf;  jobs.n[0] = NG * 512;
    jobs.src[1] = wg_hh;  jobs.dst[1] = wghh_bf;  jobs.n[1] = NG * 256;
    jobs.src[2] = wp_ih;  jobs.dst[2] = wpih_bf;  jobs.n[2] = NG * 512;
    jobs.src[3] = wp_hh;  jobs.dst[3] = wphh_bf;  jobs.n[3] = NG * 256;
    jobs.src[4] = we_ih;  jobs.dst[4] = weih_bf;  jobs.n[4] = NG * 256;
    jobs.src[5] = we_hh;  jobs.dst[5] = wehh_bf;  jobs.n[5] = NG * 256;
    jobs.src[6] = U;      jobs.dst[6] = U_bf;     jobs.n[6] = B_N * D;
    jobs.src[7] = e0;     jobs.dst[7] = e0_bf;    jobs.n[7] = B_N * D;
    jobs.src[8] = g_last; jobs.dst[8] = glast_bf; jobs.n[8] = B_N * D;
    cvt_batch<<<dim3(B_N * D / 8 / 256, 9), blk, 0, stream>>>(jobs);

    gather_q0<<<B_N * D / 4 / 256, blk, 0, stream>>>(q0, qm, q0sel_bf);
    attn_kernel<<<B_N / 4, blk, 0, stream>>>(g_hist, attn_w, c_bf, a_out);

    // global GRU: x = [U | q0_sel], h = g_hist[-1] -> g_out
    fused_gru<0><<<gridGru, blk, 0, stream>>>(
        U_bf, q0sel_bf, wgih_bf, 512, 512, bg_ih,
        glast_bf, wghh_bf, bg_hh,
        g_last, nullptr, g_out, nullptr);

    // party GRU (speaker slot): x = [U | c_], h = q0[b,qm]; writes q_out + qs bf16
    fused_gru<1><<<gridGru, blk, 0, stream>>>(
        U_bf, c_bf, wpih_bf, 512, 512, bp_ih,
        q0sel_bf, wphh_bf, bp_hh,
        q0, qm, q_out, qssel_bf);

    // emotion GRU: x = qs_sel, h = e0 -> e_out
    fused_gru<0><<<gridGru, blk, 0, stream>>>(
        qssel_bf, nullptr, weih_bf, 256, 256, be_ih,
        e0_bf, wehh_bf, be_hh,
        e0, nullptr, e_out, nullptr);
}